// Round 1
// baseline (252.105 us; speedup 1.0000x reference)
//
#include <hip/hip_runtime.h>

// Bottom-up HTMM upward pass, fully fused.
// Tree structure is implicit: starts[d] = (8^d-1)/7, children of the p-th
// parent of level d-1 are contiguous at starts[d] + (p-starts[d-1])*8 + l,
// and child position == local_index % 8 (starts[d]-1 divisible by 8).

constexpr int G_ = 16;      // NGEN
constexpr int NT_NODES = 299593;           // nodes per tree
constexpr int S0 = 0, S1 = 1, S2 = 9, S3 = 73, S4 = 585, S5 = 4681, S6 = 37449;

// ---------------- stage 0: parameter softmaxes -> tables in ws ----------------
// Layouts (float):
//   Mt  [g][i][l][j]  : 16*8*8*8 = 8192   (Mmat[l,i,j,g] = smSP[l,g]*smA[i,j,l,g])
//   smBt[m][g][c]     : 32*16*8  = 4096
//   smPit[l][g][c]    : 8*16*8   = 1024
__global__ __launch_bounds__(256) void stage0(
    const float* __restrict__ A, const float* __restrict__ B,
    const float* __restrict__ Pi, const float* __restrict__ SP,
    float* __restrict__ Mt, float* __restrict__ smBt, float* __restrict__ smPit)
{
    __shared__ float spg[8 * G_];   // smSP[l][g]
    int tid = threadIdx.x;

    if (tid < G_) {
        int g = tid;
        float v[8]; float mx = -1e30f;
        #pragma unroll
        for (int l = 0; l < 8; ++l) { v[l] = SP[l * G_ + g]; mx = fmaxf(mx, v[l]); }
        float s = 0.f;
        #pragma unroll
        for (int l = 0; l < 8; ++l) { v[l] = __expf(v[l] - mx); s += v[l]; }
        float r = 1.f / s;
        #pragma unroll
        for (int l = 0; l < 8; ++l) spg[l * G_ + g] = v[l] * r;
    }
    __syncthreads();

    // Mmat tasks: v = ((l*8 + j)*16 + g), softmax over i (stride C*K*G = 1024)
    for (int v = tid; v < 1024; v += 256) {
        int g = v & 15, rem = v >> 4, j = rem & 7, l = rem >> 3;
        float a[8]; float mx = -1e30f;
        #pragma unroll
        for (int i = 0; i < 8; ++i) { a[i] = A[((i * 8 + j) * 8 + l) * 16 + g]; mx = fmaxf(mx, a[i]); }
        float s = 0.f;
        #pragma unroll
        for (int i = 0; i < 8; ++i) { a[i] = __expf(a[i] - mx); s += a[i]; }
        float scale = spg[l * G_ + g] / s;
        #pragma unroll
        for (int i = 0; i < 8; ++i) Mt[((g * 8 + i) * 8 + l) * 8 + j] = a[i] * scale;
    }

    if (tid < 128) {
        // smB: (c,g), softmax over m (axis 1, stride G)
        int c = tid >> 4, g = tid & 15;
        float vv[32]; float mx = -1e30f;
        #pragma unroll
        for (int m = 0; m < 32; ++m) { vv[m] = B[(c * 32 + m) * 16 + g]; mx = fmaxf(mx, vv[m]); }
        float s = 0.f;
        #pragma unroll
        for (int m = 0; m < 32; ++m) { vv[m] = __expf(vv[m] - mx); s += vv[m]; }
        float r = 1.f / s;
        #pragma unroll
        for (int m = 0; m < 32; ++m) smBt[m * 128 + g * 8 + c] = vv[m] * r;
    } else {
        // smPi: (l,g), softmax over c (axis 0, stride K*G = 128)
        int v = tid - 128; int l = v >> 4, g = v & 15;
        float a[8]; float mx = -1e30f;
        #pragma unroll
        for (int c = 0; c < 8; ++c) { a[c] = Pi[(c * 8 + l) * 16 + g]; mx = fmaxf(mx, a[c]); }
        float s = 0.f;
        #pragma unroll
        for (int c = 0; c < 8; ++c) { a[c] = __expf(a[c] - mx); s += a[c]; }
        float r = 1.f / s;
        #pragma unroll
        for (int c = 0; c < 8; ++c) smPit[l * 128 + g * 8 + c] = a[c] * r;
    }
}

// ---------------- upsweep: one block = one depth-2 subtree ----------------
// Threads: tid = g*8 + i  (g = generator, i = parent hidden state).
// LEAF=true : leaves computed from smPi*smB (stage over levels 6->5->4)
// LEAF=false: 64 child betas loaded from srcBeta (stages 4->3->2 and 2->1->0)
template <bool LEAF>
__global__ __launch_bounds__(128) void upsweep(
    const float* __restrict__ Mt, const float* __restrict__ smBt,
    const float* __restrict__ smPit, const int* __restrict__ x,
    const float* __restrict__ srcBeta, float* __restrict__ dstBeta,
    float* __restrict__ llout, int bpt, int s_mid, int s_root)
{
    int b = blockIdx.x;
    int t = b / bpt;
    int loc = b - t * bpt;
    int tid = threadIdx.x;
    int g = tid >> 3, i = tid & 7;

    __shared__ __align__(16) float lvA[64 * 128];  // [n][g][c]
    __shared__ __align__(16) float lvB[8 * 128];   // [u][g][c]

    // This thread's Mmat slice: Mreg[l*8+j] = Mmat[l, i, j, g]
    float Mreg[64];
    {
        const float4* mp = (const float4*)(Mt + tid * 64);
        #pragma unroll
        for (int v = 0; v < 16; ++v) {
            float4 f = mp[v];
            Mreg[4 * v + 0] = f.x; Mreg[4 * v + 1] = f.y;
            Mreg[4 * v + 2] = f.z; Mreg[4 * v + 3] = f.w;
        }
    }

    const int nodebase = t * NT_NODES;
    float ll_acc = 0.f;

    if constexpr (LEAF) {
        // leaves: n = k*8 + i, position = n%8 = i
        const float4* pip = (const float4*)(smPit + i * 128 + g * 8);
        float4 p0 = pip[0], p1 = pip[1];
        const int leafbase = nodebase + S6 + loc * 64;
        #pragma unroll
        for (int k = 0; k < 8; ++k) {
            int n = k * 8 + i;
            int xv = x[leafbase + n];
            const float4* bp = (const float4*)(smBt + xv * 128 + g * 8);
            float4 b0 = bp[0], b1 = bp[1];
            float v0 = p0.x * b0.x, v1 = p0.y * b0.y, v2 = p0.z * b0.z, v3 = p0.w * b0.w;
            float v4 = p1.x * b1.x, v5 = p1.y * b1.y, v6 = p1.z * b1.z, v7 = p1.w * b1.w;
            float nu = ((v0 + v1) + (v2 + v3)) + ((v4 + v5) + (v6 + v7));
            ll_acc += __logf(nu);
            float r = 1.f / nu;
            float4* dst = (float4*)(lvA + n * 128 + g * 8);
            dst[0] = make_float4(v0 * r, v1 * r, v2 * r, v3 * r);
            dst[1] = make_float4(v4 * r, v5 * r, v6 * r, v7 * r);
        }
    } else {
        const float4* src = (const float4*)(srcBeta + (size_t)b * (64 * 128));
        float4* dA = (float4*)lvA;
        for (int v = tid; v < 2048; v += 128) dA[v] = src[v];
    }
    __syncthreads();

    // mid level: 8 parents u; child (position l, state j) = lvA[u*8+l][g][j]
    for (int u = 0; u < 8; ++u) {
        float tb = 0.f;
        #pragma unroll
        for (int l = 0; l < 8; ++l) {
            const float4* cp = (const float4*)(lvA + (u * 8 + l) * 128 + g * 8);
            float4 c0 = cp[0], c1 = cp[1];
            tb += c0.x * Mreg[l * 8 + 0] + c0.y * Mreg[l * 8 + 1]
                + c0.z * Mreg[l * 8 + 2] + c0.w * Mreg[l * 8 + 3];
            tb += c1.x * Mreg[l * 8 + 4] + c1.y * Mreg[l * 8 + 5]
                + c1.z * Mreg[l * 8 + 6] + c1.w * Mreg[l * 8 + 7];
        }
        int xv = x[nodebase + s_mid + loc * 8 + u];
        float bl = tb * smBt[xv * 128 + g * 8 + i];
        float nu = bl;
        nu += __shfl_xor(nu, 1); nu += __shfl_xor(nu, 2); nu += __shfl_xor(nu, 4);
        if (i == 0) ll_acc += __logf(nu);
        lvB[u * 128 + g * 8 + i] = bl / nu;
    }
    __syncthreads();

    // root of this block's subtree
    {
        float tb = 0.f;
        #pragma unroll
        for (int l = 0; l < 8; ++l) {
            const float4* cp = (const float4*)(lvB + l * 128 + g * 8);
            float4 c0 = cp[0], c1 = cp[1];
            tb += c0.x * Mreg[l * 8 + 0] + c0.y * Mreg[l * 8 + 1]
                + c0.z * Mreg[l * 8 + 2] + c0.w * Mreg[l * 8 + 3];
            tb += c1.x * Mreg[l * 8 + 4] + c1.y * Mreg[l * 8 + 5]
                + c1.z * Mreg[l * 8 + 6] + c1.w * Mreg[l * 8 + 7];
        }
        int xv = x[nodebase + s_root + loc];
        float bl = tb * smBt[xv * 128 + g * 8 + i];
        float nu = bl;
        nu += __shfl_xor(nu, 1); nu += __shfl_xor(nu, 2); nu += __shfl_xor(nu, 4);
        if (i == 0) ll_acc += __logf(nu);
        dstBeta[(size_t)b * 128 + tid] = bl / nu;
    }

    // per-block ll partial: reduce over the 8 state-lanes of each g
    float s = ll_acc;
    s += __shfl_xor(s, 1); s += __shfl_xor(s, 2); s += __shfl_xor(s, 4);
    if (i == 0) llout[b * 16 + g] = s;
}

// ---------------- final: deterministic ll sum -> out[2][16] ----------------
__global__ __launch_bounds__(256) void stage_final(
    const float* __restrict__ ll1, const float* __restrict__ ll2,
    const float* __restrict__ ll3, float* __restrict__ out)
{
    int tid = threadIdx.x;
    int col = tid & 31;          // t*16 + g
    int s = tid >> 5;            // 0..7
    int t = col >> 4, g = col & 15;
    float acc = 0.f;
    for (int k = s; k < 4096; k += 8) acc += ll1[(t * 4096 + k) * 16 + g];
    if (s == 0) {
        for (int k = 0; k < 64; ++k) acc += ll2[(t * 64 + k) * 16 + g];
        acc += ll3[t * 16 + g];
    }
    __shared__ float part[8][32];
    part[s][col] = acc;
    __syncthreads();
    if (tid < 32) {
        float sum = 0.f;
        #pragma unroll
        for (int s2 = 0; s2 < 8; ++s2) sum += part[s2][tid];
        out[tid] = sum;
    }
}

extern "C" void kernel_launch(void* const* d_in, const int* in_sizes, int n_in,
                              void* d_out, int out_size, void* d_ws, size_t ws_size,
                              hipStream_t stream)
{
    const float* A  = (const float*)d_in[0];
    const float* B  = (const float*)d_in[1];
    const float* Pi = (const float*)d_in[2];
    const float* SP = (const float*)d_in[3];
    const int*   x  = (const int*)d_in[4];

    float* ws    = (float*)d_ws;
    float* Mt    = ws;                    // 8192
    float* smBt  = Mt + 8192;             // 4096
    float* smPit = smBt + 4096;           // 1024
    float* lv4   = smPit + 1024;          // 8192*128 = 1048576
    float* lv2   = lv4 + 1048576;         // 128*128 = 16384
    float* lv0   = lv2 + 16384;           // 2*128 = 256
    float* ll1   = lv0 + 256;             // 8192*16 = 131072
    float* ll2   = ll1 + 131072;          // 128*16 = 2048
    float* ll3   = ll2 + 2048;            // 32
    float* out   = (float*)d_out;

    stage0<<<1, 256, 0, stream>>>(A, B, Pi, SP, Mt, smBt, smPit);
    // levels 6 -> 5 -> 4
    upsweep<true><<<8192, 128, 0, stream>>>(Mt, smBt, smPit, x, nullptr, lv4, ll1, 4096, S5, S4);
    // levels 4 -> 3 -> 2
    upsweep<false><<<128, 128, 0, stream>>>(Mt, smBt, smPit, x, lv4, lv2, ll2, 64, S3, S2);
    // levels 2 -> 1 -> 0
    upsweep<false><<<2, 128, 0, stream>>>(Mt, smBt, smPit, x, lv2, lv0, ll3, 1, S1, S0);
    stage_final<<<1, 256, 0, stream>>>(ll1, ll2, ll3, out);
}

// Round 2
// 130.430 us; speedup vs baseline: 1.9329x; 1.9329x over previous
//
#include <hip/hip_runtime.h>

// Bottom-up HTMM upward pass, fully fused.
// Tree structure is implicit: starts[d] = (8^d-1)/7, children of the p-th
// parent of level d-1 are contiguous at starts[d] + (p-starts[d-1])*8 + l,
// and child position == local_index % 8 (starts[d]-1 divisible by 8).

constexpr int G_ = 16;      // NGEN
constexpr int NT_NODES = 299593;           // nodes per tree
constexpr int S0 = 0, S1 = 1, S2 = 9, S3 = 73, S4 = 585, S5 = 4681, S6 = 37449;

// ---------------- stage 0: parameter softmaxes -> tables in ws ----------------
// Layouts (float):
//   Mt  [g][i][l][j]  : 16*8*8*8 = 8192   (Mmat[l,i,j,g] = smSP[l,g]*smA[i,j,l,g])
//   smBt[m][g][c]     : 32*16*8  = 4096
//   smPit[l][g][c]    : 8*16*8   = 1024
__global__ __launch_bounds__(256) void stage0(
    const float* __restrict__ A, const float* __restrict__ B,
    const float* __restrict__ Pi, const float* __restrict__ SP,
    float* __restrict__ Mt, float* __restrict__ smBt, float* __restrict__ smPit)
{
    __shared__ float spg[8 * G_];   // smSP[l][g]
    int tid = threadIdx.x;

    if (tid < G_) {
        int g = tid;
        float v[8]; float mx = -1e30f;
        #pragma unroll
        for (int l = 0; l < 8; ++l) { v[l] = SP[l * G_ + g]; mx = fmaxf(mx, v[l]); }
        float s = 0.f;
        #pragma unroll
        for (int l = 0; l < 8; ++l) { v[l] = __expf(v[l] - mx); s += v[l]; }
        float r = 1.f / s;
        #pragma unroll
        for (int l = 0; l < 8; ++l) spg[l * G_ + g] = v[l] * r;
    }
    __syncthreads();

    // Mmat tasks: v = ((l*8 + j)*16 + g), softmax over i (stride C*K*G = 1024)
    for (int v = tid; v < 1024; v += 256) {
        int g = v & 15, rem = v >> 4, j = rem & 7, l = rem >> 3;
        float a[8]; float mx = -1e30f;
        #pragma unroll
        for (int i = 0; i < 8; ++i) { a[i] = A[((i * 8 + j) * 8 + l) * 16 + g]; mx = fmaxf(mx, a[i]); }
        float s = 0.f;
        #pragma unroll
        for (int i = 0; i < 8; ++i) { a[i] = __expf(a[i] - mx); s += a[i]; }
        float scale = spg[l * G_ + g] / s;
        #pragma unroll
        for (int i = 0; i < 8; ++i) Mt[((g * 8 + i) * 8 + l) * 8 + j] = a[i] * scale;
    }

    if (tid < 128) {
        // smB: (c,g), softmax over m (axis 1, stride G)
        int c = tid >> 4, g = tid & 15;
        float vv[32]; float mx = -1e30f;
        #pragma unroll
        for (int m = 0; m < 32; ++m) { vv[m] = B[(c * 32 + m) * 16 + g]; mx = fmaxf(mx, vv[m]); }
        float s = 0.f;
        #pragma unroll
        for (int m = 0; m < 32; ++m) { vv[m] = __expf(vv[m] - mx); s += vv[m]; }
        float r = 1.f / s;
        #pragma unroll
        for (int m = 0; m < 32; ++m) smBt[m * 128 + g * 8 + c] = vv[m] * r;
    } else {
        // smPi: (l,g), softmax over c (axis 0, stride K*G = 128)
        int v = tid - 128; int l = v >> 4, g = v & 15;
        float a[8]; float mx = -1e30f;
        #pragma unroll
        for (int c = 0; c < 8; ++c) { a[c] = Pi[(c * 8 + l) * 16 + g]; mx = fmaxf(mx, a[c]); }
        float s = 0.f;
        #pragma unroll
        for (int c = 0; c < 8; ++c) { a[c] = __expf(a[c] - mx); s += a[c]; }
        float r = 1.f / s;
        #pragma unroll
        for (int c = 0; c < 8; ++c) smPit[l * 128 + g * 8 + c] = a[c] * r;
    }
}

// ---------------- upsweep: one block = one depth-2 subtree ----------------
// Threads: tid = g*8 + i  (g = generator, i = parent hidden state).
// LEAF=true : leaves computed from smPi*smB (stage over levels 6->5->4)
// LEAF=false: 64 child betas loaded from srcBeta (stages 4->3->2 and 2->1->0)
// llin != nullptr: additionally reduce 64 rows [b*64, b*64+64) of the previous
// stage's per-block ll partials into this block's ll output (deterministic).
template <bool LEAF>
__global__ __launch_bounds__(128) void upsweep(
    const float* __restrict__ Mt, const float* __restrict__ smBt,
    const float* __restrict__ smPit, const int* __restrict__ x,
    const float* __restrict__ srcBeta, float* __restrict__ dstBeta,
    float* __restrict__ llout, const float* __restrict__ llin,
    int bpt, int s_mid, int s_root)
{
    int b = blockIdx.x;
    int t = b / bpt;
    int loc = b - t * bpt;
    int tid = threadIdx.x;
    int g = tid >> 3, i = tid & 7;

    __shared__ __align__(16) float lvA[64 * 128];  // [n][g][c]
    __shared__ __align__(16) float lvB[8 * 128];   // [u][g][c]

    float ll_acc = 0.f;
    if (llin) {
        // rows b*64 + i*8 + k, column g; 8 independent loads
        const float* p = llin + ((size_t)b * 64 + (size_t)i * 8) * 16 + g;
        float a0 = p[0], a1 = p[16], a2 = p[32], a3 = p[48];
        float a4 = p[64], a5 = p[80], a6 = p[96], a7 = p[112];
        ll_acc = ((a0 + a1) + (a2 + a3)) + ((a4 + a5) + (a6 + a7));
    }

    // This thread's Mmat slice: Mreg[l*8+j] = Mmat[l, i, j, g]
    float Mreg[64];
    {
        const float4* mp = (const float4*)(Mt + tid * 64);
        #pragma unroll
        for (int v = 0; v < 16; ++v) {
            float4 f = mp[v];
            Mreg[4 * v + 0] = f.x; Mreg[4 * v + 1] = f.y;
            Mreg[4 * v + 2] = f.z; Mreg[4 * v + 3] = f.w;
        }
    }

    const int nodebase = t * NT_NODES;

    if constexpr (LEAF) {
        // leaves: n = k*8 + i, position = n%8 = i
        const float4* pip = (const float4*)(smPit + i * 128 + g * 8);
        float4 p0 = pip[0], p1 = pip[1];
        const int leafbase = nodebase + S6 + loc * 64;
        #pragma unroll
        for (int k = 0; k < 8; ++k) {
            int n = k * 8 + i;
            int xv = x[leafbase + n];
            const float4* bp = (const float4*)(smBt + xv * 128 + g * 8);
            float4 b0 = bp[0], b1 = bp[1];
            float v0 = p0.x * b0.x, v1 = p0.y * b0.y, v2 = p0.z * b0.z, v3 = p0.w * b0.w;
            float v4 = p1.x * b1.x, v5 = p1.y * b1.y, v6 = p1.z * b1.z, v7 = p1.w * b1.w;
            float nu = ((v0 + v1) + (v2 + v3)) + ((v4 + v5) + (v6 + v7));
            ll_acc += __logf(nu);
            float r = 1.f / nu;
            float4* dst = (float4*)(lvA + n * 128 + g * 8);
            dst[0] = make_float4(v0 * r, v1 * r, v2 * r, v3 * r);
            dst[1] = make_float4(v4 * r, v5 * r, v6 * r, v7 * r);
        }
    } else {
        const float4* src = (const float4*)(srcBeta + (size_t)b * (64 * 128));
        float4* dA = (float4*)lvA;
        for (int v = tid; v < 2048; v += 128) dA[v] = src[v];
    }
    __syncthreads();

    // mid level: 8 parents u; child (position l, state j) = lvA[u*8+l][g][j]
    // 4 independent accumulator chains for ILP (no fast-math reassociation).
    for (int u = 0; u < 8; ++u) {
        float t0 = 0.f, t1 = 0.f, t2 = 0.f, t3 = 0.f;
        #pragma unroll
        for (int l = 0; l < 8; ++l) {
            const float4* cp = (const float4*)(lvA + (u * 8 + l) * 128 + g * 8);
            float4 c0 = cp[0], c1 = cp[1];
            t0 += c0.x * Mreg[l * 8 + 0]; t1 += c0.y * Mreg[l * 8 + 1];
            t2 += c0.z * Mreg[l * 8 + 2]; t3 += c0.w * Mreg[l * 8 + 3];
            t0 += c1.x * Mreg[l * 8 + 4]; t1 += c1.y * Mreg[l * 8 + 5];
            t2 += c1.z * Mreg[l * 8 + 6]; t3 += c1.w * Mreg[l * 8 + 7];
        }
        float tb = (t0 + t1) + (t2 + t3);
        int xv = x[nodebase + s_mid + loc * 8 + u];
        float bl = tb * smBt[xv * 128 + g * 8 + i];
        float nu = bl;
        nu += __shfl_xor(nu, 1); nu += __shfl_xor(nu, 2); nu += __shfl_xor(nu, 4);
        if (i == 0) ll_acc += __logf(nu);
        lvB[u * 128 + g * 8 + i] = bl / nu;
    }
    __syncthreads();

    // root of this block's subtree
    {
        float t0 = 0.f, t1 = 0.f, t2 = 0.f, t3 = 0.f;
        #pragma unroll
        for (int l = 0; l < 8; ++l) {
            const float4* cp = (const float4*)(lvB + l * 128 + g * 8);
            float4 c0 = cp[0], c1 = cp[1];
            t0 += c0.x * Mreg[l * 8 + 0]; t1 += c0.y * Mreg[l * 8 + 1];
            t2 += c0.z * Mreg[l * 8 + 2]; t3 += c0.w * Mreg[l * 8 + 3];
            t0 += c1.x * Mreg[l * 8 + 4]; t1 += c1.y * Mreg[l * 8 + 5];
            t2 += c1.z * Mreg[l * 8 + 6]; t3 += c1.w * Mreg[l * 8 + 7];
        }
        float tb = (t0 + t1) + (t2 + t3);
        int xv = x[nodebase + s_root + loc];
        float bl = tb * smBt[xv * 128 + g * 8 + i];
        float nu = bl;
        nu += __shfl_xor(nu, 1); nu += __shfl_xor(nu, 2); nu += __shfl_xor(nu, 4);
        if (i == 0) ll_acc += __logf(nu);
        dstBeta[(size_t)b * 128 + tid] = bl / nu;
    }

    // per-block ll partial: reduce over the 8 state-lanes of each g
    float s = ll_acc;
    s += __shfl_xor(s, 1); s += __shfl_xor(s, 2); s += __shfl_xor(s, 4);
    if (i == 0) llout[b * 16 + g] = s;
}

extern "C" void kernel_launch(void* const* d_in, const int* in_sizes, int n_in,
                              void* d_out, int out_size, void* d_ws, size_t ws_size,
                              hipStream_t stream)
{
    const float* A  = (const float*)d_in[0];
    const float* B  = (const float*)d_in[1];
    const float* Pi = (const float*)d_in[2];
    const float* SP = (const float*)d_in[3];
    const int*   x  = (const int*)d_in[4];

    float* ws    = (float*)d_ws;
    float* Mt    = ws;                    // 8192
    float* smBt  = Mt + 8192;             // 4096
    float* smPit = smBt + 4096;           // 1024
    float* lv4   = smPit + 1024;          // 8192*128 = 1048576
    float* lv2   = lv4 + 1048576;         // 128*128 = 16384
    float* lv0   = lv2 + 16384;           // 2*128 = 256
    float* ll1   = lv0 + 256;             // 8192*16 = 131072
    float* ll2   = ll1 + 131072;          // 128*16 = 2048
    float* out   = (float*)d_out;

    stage0<<<1, 256, 0, stream>>>(A, B, Pi, SP, Mt, smBt, smPit);
    // levels 6 -> 5 -> 4
    upsweep<true><<<8192, 128, 0, stream>>>(Mt, smBt, smPit, x, nullptr, lv4, ll1,
                                            nullptr, 4096, S5, S4);
    // levels 4 -> 3 -> 2  (+ fold in ll1 chunks)
    upsweep<false><<<128, 128, 0, stream>>>(Mt, smBt, smPit, x, lv4, lv2, ll2,
                                            ll1, 64, S3, S2);
    // levels 2 -> 1 -> 0  (+ fold in ll2 chunks), writes out[2][16] directly
    upsweep<false><<<2, 128, 0, stream>>>(Mt, smBt, smPit, x, lv2, lv0, out,
                                          ll2, 1, S1, S0);
}